// Round 7
// baseline (287.889 us; speedup 1.0000x reference)
//
#include <hip/hip_runtime.h>
#include <hip/hip_bf16.h>
#include <math.h>

#define D_MODEL 1024
#define N_HEADS 16
#define D_K 64
#define N_CLASSES 32
#define S_LEN 16
#define BATCH 32
#define T_LEN 512

typedef __bf16 bf16_t;
typedef bf16_t bf16x8 __attribute__((ext_vector_type(8)));
typedef float f32x4 __attribute__((ext_vector_type(4)));

__device__ inline unsigned short f2bf(float f) {
    unsigned int u = __float_as_uint(f);
    unsigned int r = (u + 0x7FFFu + ((u >> 16) & 1u)) >> 16;   // RNE
    return (unsigned short)r;
}
__device__ inline float4 tanh4(float4 v) {
    return make_float4(tanhf(v.x), tanhf(v.y), tanhf(v.z), tanhf(v.w));
}
__device__ inline float dot4(float4 a, float4 b) {
    return a.x * b.x + a.y * b.y + a.z * b.z + a.w * b.w;
}
// pack 4 floats -> 4 e4m3 bytes (OCP, HW cvt)
__device__ inline int pack_fp8x4(float4 v) {
    int p = __builtin_amdgcn_cvt_pk_fp8_f32(v.x, v.y, 0, false);
    p = __builtin_amdgcn_cvt_pk_fp8_f32(v.z, v.w, p, true);
    return p;
}

// async global->LDS, 16 bytes per lane (global_load_lds_dwordx4)
__device__ inline void async16(void* lds, const void* g) {
    __builtin_amdgcn_global_load_lds(
        (const __attribute__((address_space(1))) unsigned int*)g,
        (__attribute__((address_space(3))) unsigned int*)lds, 16, 0, 0);
}

// ---------------- fp32 -> fp8 e4m3 conversion, two arrays, per-array scale --
// scale pre-multiplies values (WK ~ N(0,1e-3) is subnormal in e4m3 -> x512).
__global__ __launch_bounds__(256) void cvt2_fp8(
    const float4* __restrict__ inA, int* __restrict__ outA, int nA4, float sA,
    const float4* __restrict__ inB, int* __restrict__ outB, int nB4, float sB)
{
    int i = blockIdx.x * 256 + threadIdx.x;
    const float4* in;
    int* out;
    float s;
    if (i < nA4) { in = inA + i; out = outA + i; s = sA; }
    else {
        i -= nA4;
        if (i >= nB4) return;
        in = inB + i; out = outB + i; s = sB;
    }
    float4 v = *in;
    v.x *= s; v.y *= s; v.z *= s; v.w *= s;
    *out = pack_fp8x4(v);
}

// ---------------- fp32 -> bf16 conversion, two arrays per launch ------------
__global__ __launch_bounds__(256) void cvt2_bf16(
    const float4* __restrict__ inA, ushort4* __restrict__ outA, int nA4,
    const float4* __restrict__ inB, ushort4* __restrict__ outB, int nB4)
{
    int i = blockIdx.x * 256 + threadIdx.x;
    const float4* in;
    ushort4* out;
    if (i < nA4) { in = inA + i; out = outA + i; }
    else {
        i -= nA4;
        if (i >= nB4) return;
        in = inB + i; out = outB + i;
    }
    float4 v = *in;
    ushort4 o;
    o.x = f2bf(v.x); o.y = f2bf(v.y); o.z = f2bf(v.z); o.w = f2bf(v.w);
    *out = o;
}

__global__ __launch_bounds__(256) void cvt_bf16(
    const float4* __restrict__ in, ushort4* __restrict__ out, int n4)
{
    int i = blockIdx.x * 256 + threadIdx.x;
    if (i < n4) {
        float4 v = in[i];
        ushort4 o;
        o.x = f2bf(v.x); o.y = f2bf(v.y); o.z = f2bf(v.z); o.w = f2bf(v.w);
        out[i] = o;
    }
}

// ---------------- fp8 MFMA GEMM: C = bf16(tanh(outScale * (A @ B^T))) -------
// A: (M,K) e4m3 row-major, B: (N,K) e4m3 row-major (pre-scaled), C bf16.
// 128x128 tile, BK=64 BYTES (same 16 KB staged/iter as the bf16 BK=32 kernel
// but 2x the K -> 16 iters instead of 32). Round-6 counters showed the K-loop
// is staging-throughput-bound (MfmaUtil 18%, iter ~430cy), so halving
// bytes/MAC is the lever. m-fast grid for XCD A-reuse (round-6 win).
__global__ __launch_bounds__(256) void gemm_fp8_bt(
    const unsigned char* __restrict__ A, const unsigned char* __restrict__ B,
    unsigned short* __restrict__ C, int M, int N, int K, float outScale)
{
    __shared__ unsigned char As[128 * 64];   // 8 KB
    __shared__ unsigned char Bs[128 * 64];   // 8 KB
    const int tid = threadIdx.x;
    const int m0 = blockIdx.x * 128;
    const int n0 = blockIdx.y * 128;
    const int wid = tid >> 6;
    const int lane = tid & 63;
    const int quad = lane >> 4;
    const int l16 = lane & 15;
    const int wm = (wid >> 1) * 64;
    const int wn = (wid & 1) * 64;

    f32x4 acc[4][4] = {};

    const int r0 = tid >> 2;           // staging row 0..63
    const int cc0 = (tid & 3) * 16;    // byte offset within 64

    for (int k0 = 0; k0 < K; k0 += 64) {
        async16(&As[tid * 16],        A + (size_t)(m0 + r0) * K + k0 + cc0);
        async16(&As[4096 + tid * 16], A + (size_t)(m0 + 64 + r0) * K + k0 + cc0);
        async16(&Bs[tid * 16],        B + (size_t)(n0 + r0) * K + k0 + cc0);
        async16(&Bs[4096 + tid * 16], B + (size_t)(n0 + 64 + r0) * K + k0 + cc0);
        __syncthreads();

        long a8[4][2], b8[4][2];
#pragma unroll
        for (int mt = 0; mt < 4; mt++)
#pragma unroll
            for (int kh = 0; kh < 2; kh++)
                a8[mt][kh] = *(const long*)&As[(wm + mt * 16 + l16) * 64 + kh * 32 + quad * 8];
#pragma unroll
        for (int nt = 0; nt < 4; nt++)
#pragma unroll
            for (int kh = 0; kh < 2; kh++)
                b8[nt][kh] = *(const long*)&Bs[(wn + nt * 16 + l16) * 64 + kh * 32 + quad * 8];
#pragma unroll
        for (int mt = 0; mt < 4; mt++)
#pragma unroll
            for (int nt = 0; nt < 4; nt++) {
                acc[mt][nt] = __builtin_amdgcn_mfma_f32_16x16x32_fp8_fp8(
                    a8[mt][0], b8[nt][0], acc[mt][nt], 0, 0, 0);
                acc[mt][nt] = __builtin_amdgcn_mfma_f32_16x16x32_fp8_fp8(
                    a8[mt][1], b8[nt][1], acc[mt][nt], 0, 0, 0);
            }
        __syncthreads();
    }

#pragma unroll
    for (int mt = 0; mt < 4; mt++)
#pragma unroll
        for (int nt = 0; nt < 4; nt++)
#pragma unroll
            for (int r = 0; r < 4; r++) {
                const int row = m0 + wm + mt * 16 + quad * 4 + r;
                const int col = n0 + wn + nt * 16 + l16;
                C[(size_t)row * N + col] = f2bf(tanhf(acc[mt][nt][r] * outScale));
            }
}

// ---------------- bf16 MFMA GEMM (qproj): C = A @ B^T, bf16 out -------------
__global__ __launch_bounds__(256) void gemm_bf16_bt(
    const unsigned short* __restrict__ A, const unsigned short* __restrict__ B,
    unsigned short* __restrict__ C, int M, int N, int K)
{
    __shared__ unsigned short As[128 * 32];   // 8 KB
    __shared__ unsigned short Bs[128 * 32];   // 8 KB
    const int tid = threadIdx.x;
    const int m0 = blockIdx.x * 128;
    const int n0 = blockIdx.y * 128;
    const int wid = tid >> 6;
    const int lane = tid & 63;
    const int quad = lane >> 4;
    const int l16 = lane & 15;
    const int wm = (wid >> 1) * 64;
    const int wn = (wid & 1) * 64;

    f32x4 acc[4][4] = {};

    const int r0 = tid >> 2;
    const int cc0 = (tid & 3) * 8;

    for (int k0 = 0; k0 < K; k0 += 32) {
        async16(&As[tid * 8],        A + (size_t)(m0 + r0) * K + k0 + cc0);
        async16(&As[2048 + tid * 8], A + (size_t)(m0 + 64 + r0) * K + k0 + cc0);
        async16(&Bs[tid * 8],        B + (size_t)(n0 + r0) * K + k0 + cc0);
        async16(&Bs[2048 + tid * 8], B + (size_t)(n0 + 64 + r0) * K + k0 + cc0);
        __syncthreads();

        bf16x8 af[4], bfr[4];
#pragma unroll
        for (int mt = 0; mt < 4; mt++)
            af[mt] = *(const bf16x8*)&As[(wm + mt * 16 + l16) * 32 + quad * 8];
#pragma unroll
        for (int nt = 0; nt < 4; nt++)
            bfr[nt] = *(const bf16x8*)&Bs[(wn + nt * 16 + l16) * 32 + quad * 8];
#pragma unroll
        for (int mt = 0; mt < 4; mt++)
#pragma unroll
            for (int nt = 0; nt < 4; nt++)
                acc[mt][nt] = __builtin_amdgcn_mfma_f32_16x16x32_bf16(
                    af[mt], bfr[nt], acc[mt][nt], 0, 0, 0);
        __syncthreads();
    }

#pragma unroll
    for (int mt = 0; mt < 4; mt++)
#pragma unroll
        for (int nt = 0; nt < 4; nt++)
#pragma unroll
            for (int r = 0; r < 4; r++) {
                const int row = m0 + wm + mt * 16 + quad * 4 + r;
                const int col = n0 + wn + nt * 16 + l16;
                C[(size_t)row * N + col] = f2bf(acc[mt][nt][r]);
            }
}

// ---------------- wql = ql @ WV^T (32 x 1024, K=1024), fp32, split-K -------
__global__ __launch_bounds__(256) void wql_kernel(
    const float* __restrict__ ql, const float* __restrict__ WV, float* __restrict__ wql)
{
    __shared__ float4 qls[32][32];      // [c][kq]   16 KB
    __shared__ float4 WVs[64][33];      // [n][kq]+pad 33.8 KB
    const int tid = threadIdx.x;
    const int n0 = blockIdx.x * 64;
    const int k0 = blockIdx.y * 128;

    for (int i = tid; i < 1024; i += 256)
        qls[i >> 5][i & 31] = *(const float4*)(ql + (size_t)(i >> 5) * D_MODEL + k0 + (i & 31) * 4);
    for (int i = tid; i < 2048; i += 256)
        WVs[i >> 5][i & 31] = *(const float4*)(WV + (size_t)(n0 + (i >> 5)) * D_MODEL + k0 + (i & 31) * 4);
    __syncthreads();

    const int n = tid & 63;
    const int c0 = (tid >> 6) * 8;
    float acc[8] = {};
    for (int kq = 0; kq < 32; kq++) {
        const float4 wv = WVs[n][kq];
#pragma unroll
        for (int c = 0; c < 8; c++) acc[c] += dot4(qls[c0 + c][kq], wv);
    }
#pragma unroll
    for (int c = 0; c < 8; c++)
        atomicAdd(&wql[(size_t)(c0 + c) * D_MODEL + n0 + n], acc[c]);
}

// ---------------- KV via MFMA ------------------------------------------------
// kv[((b*16+z)*32 + c)*512 + t] = sum_h tanh(H[b,t,z*64+h]) * wql[c,z*64+h]
__global__ __launch_bounds__(256) void kv_gemm(
    const float* __restrict__ H, const unsigned short* __restrict__ wql16,
    float* __restrict__ kv)
{
    __shared__ unsigned short Ks[128 * 64];  // 16 KB   [tl][h] bf16
    __shared__ float kvt[128 * 33];          // 16.9 KB [tl][c] padded
    const int chunk = blockIdx.x;
    const int z = blockIdx.y;
    const int b = chunk >> 2;
    const int t0 = (chunk & 3) * 128;
    const int tid = threadIdx.x;
    const int wid = tid >> 6;
    const int lane = tid & 63;
    const int quad = lane >> 4;
    const int l16 = lane & 15;

#pragma unroll
    for (int it = 0; it < 8; it++) {
        const int idx = it * 256 + tid;
        const int row = idx >> 4;
        const int c4 = (idx & 15) * 4;
        float4 v = *(const float4*)(H + ((size_t)b * T_LEN + t0 + row) * D_MODEL + z * D_K + c4);
        v = tanh4(v);
        ushort4 o;
        o.x = f2bf(v.x); o.y = f2bf(v.y); o.z = f2bf(v.z); o.w = f2bf(v.w);
        *(ushort4*)&Ks[row * 64 + c4] = o;
    }
    bf16x8 bfr[2][2];
#pragma unroll
    for (int ct = 0; ct < 2; ct++)
#pragma unroll
        for (int kh = 0; kh < 2; kh++)
            bfr[ct][kh] = *(const bf16x8*)(wql16 +
                (size_t)(ct * 16 + l16) * D_MODEL + z * D_K + kh * 32 + quad * 8);
    __syncthreads();

    const int wt = wid * 32;
    f32x4 acc[2][2] = {};
#pragma unroll
    for (int tt = 0; tt < 2; tt++) {
        const bf16x8 a0 = *(const bf16x8*)&Ks[(wt + tt * 16 + l16) * 64 + quad * 8];
        const bf16x8 a1 = *(const bf16x8*)&Ks[(wt + tt * 16 + l16) * 64 + 32 + quad * 8];
#pragma unroll
        for (int ct = 0; ct < 2; ct++) {
            acc[tt][ct] = __builtin_amdgcn_mfma_f32_16x16x32_bf16(a0, bfr[ct][0], acc[tt][ct], 0, 0, 0);
            acc[tt][ct] = __builtin_amdgcn_mfma_f32_16x16x32_bf16(a1, bfr[ct][1], acc[tt][ct], 0, 0, 0);
        }
    }
#pragma unroll
    for (int tt = 0; tt < 2; tt++)
#pragma unroll
        for (int ct = 0; ct < 2; ct++)
#pragma unroll
            for (int r = 0; r < 4; r++)
                kvt[(wt + tt * 16 + quad * 4 + r) * 33 + ct * 16 + l16] = acc[tt][ct][r];
    __syncthreads();

    float* outb = kv + (((size_t)b * 16 + z) * 32) * 512 + t0;
#pragma unroll
    for (int it = 0; it < 4; it++) {
        const int idx = it * 256 + tid;
        const int c = idx >> 5;
        const int tq = (idx & 31) * 4;
        float4 v = make_float4(kvt[(tq + 0) * 33 + c], kvt[(tq + 1) * 33 + c],
                               kvt[(tq + 2) * 33 + c], kvt[(tq + 3) * 33 + c]);
        *(float4*)(outb + (size_t)c * 512 + tq) = v;
    }
}

// ---------------- Attention via MFMA: block per (b,z), 4 waves x 8 c-tiles ---
__global__ __launch_bounds__(256) void attn_mfma(
    const unsigned short* __restrict__ qproj, const unsigned short* __restrict__ wkt,
    const float* __restrict__ kv, float* __restrict__ out)
{
    __shared__ unsigned short wkts[512 * 64];   // 64 KB, [t][k]
    const int z = blockIdx.x;
    const int b = blockIdx.y;
    const int tid = threadIdx.x;
    const int wid = tid >> 6;
    const int lane = tid & 63;
    const int quad = lane >> 4;
    const int l16 = lane & 15;

    const unsigned short* wb = wkt + (size_t)(b * T_LEN) * D_MODEL + z * D_K;
#pragma unroll
    for (int it = 0; it < 16; it++) {
        const int chunk = it * 256 + tid;
        async16(&wkts[chunk * 8], wb + (size_t)(chunk >> 3) * D_MODEL + (chunk & 7) * 8);
    }

    bf16x8 af[8][2];
#pragma unroll
    for (int ct = 0; ct < 8; ct++)
#pragma unroll
        for (int kh = 0; kh < 2; kh++)
            af[ct][kh] = *(const bf16x8*)(qproj +
                (size_t)((wid * 8 + ct) * 16 + l16) * D_MODEL + z * D_K + kh * 32 + quad * 8);
    __syncthreads();

    float den[8][4], num[8][4];
#pragma unroll
    for (int ct = 0; ct < 8; ct++)
#pragma unroll
        for (int r = 0; r < 4; r++) { den[ct][r] = 0.f; num[ct][r] = 0.f; }

    const float* kvb = kv + (((size_t)b * 16 + z) * 32) * 512;
    for (int nt = 0; nt < 32; nt++) {
        const bf16x8 b0 = *(const bf16x8*)&wkts[(nt * 16 + l16) * 64 + quad * 8];
        const bf16x8 b1 = *(const bf16x8*)&wkts[(nt * 16 + l16) * 64 + 32 + quad * 8];
#pragma unroll
        for (int ct = 0; ct < 8; ct++) {
            f32x4 a = {};
            a = __builtin_amdgcn_mfma_f32_16x16x32_bf16(af[ct][0], b0, a, 0, 0, 0);
            a = __builtin_amdgcn_mfma_f32_16x16x32_bf16(af[ct][1], b1, a, 0, 0, 0);
            const float kvv = kvb[(size_t)(wid * 8 + ct) * 512 + nt * 16 + l16];
#pragma unroll
            for (int r = 0; r < 4; r++) {
                const float e = __expf(a[r]);
                den[ct][r] += e;
                num[ct][r] += e * kvv;
            }
        }
    }

#pragma unroll
    for (int ct = 0; ct < 8; ct++) {
        float s = 0.f;
#pragma unroll
        for (int r = 0; r < 4; r++) {
            float d = den[ct][r], n = num[ct][r];
#pragma unroll
            for (int off = 1; off < 16; off <<= 1) {
                d += __shfl_xor(d, off, 64);
                n += __shfl_xor(n, off, 64);
            }
            s += n / d;
        }
        s += __shfl_xor(s, 16, 64);
        s += __shfl_xor(s, 32, 64);
        if (lane == 0)
            atomicAdd(&out[b * N_CLASSES + wid * 8 + ct], s * (1.0f / 16.0f));
    }
}

extern "C" void kernel_launch(void* const* d_in, const int* in_sizes, int n_in,
                              void* d_out, int out_size, void* d_ws, size_t ws_size,
                              hipStream_t stream)
{
    const float* Q  = (const float*)d_in[0];   // (32,16,1024)
    const float* H  = (const float*)d_in[1];   // (32,512,1024)
    const float* ql = (const float*)d_in[2];   // (32,1024)
    const float* WQ = (const float*)d_in[3];   // (1024,1024)
    const float* WK = (const float*)d_in[4];
    const float* WV = (const float*)d_in[5];
    float* out = (float*)d_out;                // (32,32)

    char* ws = (char*)d_ws;
    // region A (0..33.5MB): Hf8 first (16.7MB); dead after wkt GEMM -> overlaid
    unsigned char*  Hf8   = (unsigned char*)(ws);                        // 16.7 MB
    unsigned short* wkt_b = (unsigned short*)(ws + (size_t)33554432);    // 33.5 MB
    float*          kv    = (float*)(ws + (size_t)67108864);             // 33.5 MB
    unsigned char*  WKf8  = (unsigned char*)(ws + (size_t)100663296);    // 1 MB
    // overlays into region A (written only after wkt GEMM):
    unsigned short* Qb      = (unsigned short*)(ws);                     // 1 MB
    unsigned short* WQb     = (unsigned short*)(ws + (size_t)(1 << 20)); // 2 MB
    unsigned short* qproj_b = (unsigned short*)(ws + (size_t)(3 << 20)); // 1 MB
    float*          wqlb    = (float*)(ws + (size_t)(4 << 20));          // 128 KB
    unsigned short* wqlb16  = (unsigned short*)(ws + (size_t)4718592);   // 64 KB

    hipMemsetAsync(d_out, 0, (size_t)out_size * sizeof(float), stream);

    dim3 thr(256);
    // fp8 conversions: H (scale 1), WK (scale 512: N(0,1e-3) is subnormal in e4m3)
    cvt2_fp8<<<dim3(17408), thr, 0, stream>>>(
        (const float4*)H, (int*)Hf8, 4194304, 1.0f,
        (const float4*)WK, (int*)WKf8, 262144, 512.0f);
    // wkt = tanh((H8 @ WK8^T)/512)  (16384 x 1024), bf16 out. m-fast grid.
    gemm_fp8_bt<<<dim3(128, 8), thr, 0, stream>>>(Hf8, WKf8, wkt_b, 16384, 1024, 1024, 1.0f / 512.0f);
    // Hf8 dead -> overlay region A (Q + WQ bf16)
    cvt2_bf16<<<dim3(1536), thr, 0, stream>>>(
        (const float4*)Q, (ushort4*)Qb, 131072,
        (const float4*)WQ, (ushort4*)WQb, 262144);
    // qproj = Q @ WQ^T  (512 x 1024), bf16
    gemm_bf16_bt<<<dim3(4, 8), thr, 0, stream>>>(Qb, WQb, qproj_b, 512, 1024, 1024);
    // zero wqlb ONLY NOW (overlay ordering: cvt2_bf16 above writes 0..3MB)
    hipMemsetAsync(wqlb, 0, (size_t)N_CLASSES * D_MODEL * sizeof(float), stream);
    // Wql = ql @ WV^T  (32 x 1024), fp32 split-K
    wql_kernel<<<dim3(16, 8), thr, 0, stream>>>(ql, WV, wqlb);
    // wql -> bf16 for the kv MFMA
    cvt_bf16<<<dim3(32), thr, 0, stream>>>((const float4*)wqlb, (ushort4*)wqlb16, 8192);
    // kv(b,z,c,t) via MFMA
    kv_gemm<<<dim3(128, 16), thr, 0, stream>>>(H, wqlb16, kv);
    // fused scores -> softmax -> dot(kv) -> mean_s, atomic over z
    attn_mfma<<<dim3(16, 32), thr, 0, stream>>>(qproj_b, wkt_b, kv, out);
}

// Round 8
// 248.191 us; speedup vs baseline: 1.1599x; 1.1599x over previous
//
#include <hip/hip_runtime.h>
#include <hip/hip_bf16.h>
#include <math.h>

#define D_MODEL 1024
#define N_HEADS 16
#define D_K 64
#define N_CLASSES 32
#define S_LEN 16
#define BATCH 32
#define T_LEN 512

typedef __bf16 bf16_t;
typedef bf16_t bf16x8 __attribute__((ext_vector_type(8)));
typedef float f32x4 __attribute__((ext_vector_type(4)));
typedef long lx2 __attribute__((ext_vector_type(2)));

__device__ inline unsigned short f2bf(float f) {
    unsigned int u = __float_as_uint(f);
    unsigned int r = (u + 0x7FFFu + ((u >> 16) & 1u)) >> 16;   // RNE
    return (unsigned short)r;
}
// fast tanh: (e-1)/(e+1), e = exp(2x). ~6 VALU vs ~70 for libm tanhf.
// Valid for |x| < 40 (our inputs: |x| <= ~6). rel err ~1e-6.
__device__ inline float fast_tanh(float x) {
    float e = __expf(2.0f * x);
    return (e - 1.0f) * __builtin_amdgcn_rcpf(e + 1.0f);
}
__device__ inline float4 fast_tanh4(float4 v) {
    return make_float4(fast_tanh(v.x), fast_tanh(v.y), fast_tanh(v.z), fast_tanh(v.w));
}
__device__ inline float dot4(float4 a, float4 b) {
    return a.x * b.x + a.y * b.y + a.z * b.z + a.w * b.w;
}
// pack 4 floats -> 4 e4m3 bytes (OCP, HW cvt)
__device__ inline int pack_fp8x4(float4 v) {
    int p = __builtin_amdgcn_cvt_pk_fp8_f32(v.x, v.y, 0, false);
    p = __builtin_amdgcn_cvt_pk_fp8_f32(v.z, v.w, p, true);
    return p;
}

// async global->LDS, 16 bytes per lane (global_load_lds_dwordx4)
__device__ inline void async16(void* lds, const void* g) {
    __builtin_amdgcn_global_load_lds(
        (const __attribute__((address_space(1))) unsigned int*)g,
        (__attribute__((address_space(3))) unsigned int*)lds, 16, 0, 0);
}

// ---------------- fp32 -> fp8 e4m3, MFMA-FRAGMENT-SWIZZLED layout -----------
// Source: (R, 1024) fp32 row-major. Output: for each 16-row x 64-byte subtile
// (rb, kb), a 1024B block at ((rb*16 + kb)*1024) where byte position
// (quad*16+l16)*16 + kh*8 + b holds src[rb*16+l16][kb*64+kh*32+quad*8+b].
// => staging waves read lane-linear 1024B blocks (coalesced), and each MFMA
//    lane reads its whole K=64 fragment as ONE conflict-free ds_read_b128 at
//    lane*16 (round-7's b64 reads were 8-way bank-conflicted: 29.4M cycles).
__global__ __launch_bounds__(256) void cvt2_fp8_sw(
    const float* __restrict__ inA, int* __restrict__ outA, int nA,
    const float* __restrict__ inB, int* __restrict__ outB, int nB, float sB)
{
    int i = blockIdx.x * 256 + threadIdx.x;
    const float* in;
    int* out;
    float s;
    if (i < nA) { in = inA; out = outA; s = 1.0f; }
    else {
        i -= nA;
        if (i >= nB) return;
        in = inB; out = outB; s = sB;
    }
    const int p = i << 2;             // byte index in swizzled output
    const int blk = p >> 10;          // 1024B block
    const int pos = p & 1023;
    const int rb = blk >> 4;          // KB = 1024/64 = 16 k-blocks per row-block
    const int kb = blk & 15;
    const int q = pos >> 4;           // chunk 0..63
    const int quad = q >> 4, l16 = q & 15;
    const int o = pos & 15;           // 0,4,8,12
    const int kh = o >> 3, b0 = o & 7;
    const int r = rb * 16 + l16;
    const int k = kb * 64 + kh * 32 + quad * 8 + b0;
    float4 v = *(const float4*)(in + (size_t)r * 1024 + k);
    v.x *= s; v.y *= s; v.z *= s; v.w *= s;
    out[i] = pack_fp8x4(v);
}

// ---------------- fp32 -> bf16 conversion, two arrays per launch ------------
__global__ __launch_bounds__(256) void cvt2_bf16(
    const float4* __restrict__ inA, ushort4* __restrict__ outA, int nA4,
    const float4* __restrict__ inB, ushort4* __restrict__ outB, int nB4)
{
    int i = blockIdx.x * 256 + threadIdx.x;
    const float4* in;
    ushort4* out;
    if (i < nA4) { in = inA + i; out = outA + i; }
    else {
        i -= nA4;
        if (i >= nB4) return;
        in = inB + i; out = outB + i;
    }
    float4 v = *in;
    ushort4 o;
    o.x = f2bf(v.x); o.y = f2bf(v.y); o.z = f2bf(v.z); o.w = f2bf(v.w);
    *out = o;
}

__global__ __launch_bounds__(256) void cvt_bf16(
    const float4* __restrict__ in, ushort4* __restrict__ out, int n4)
{
    int i = blockIdx.x * 256 + threadIdx.x;
    if (i < n4) {
        float4 v = in[i];
        ushort4 o;
        o.x = f2bf(v.x); o.y = f2bf(v.y); o.z = f2bf(v.z); o.w = f2bf(v.w);
        out[i] = o;
    }
}

// ---------------- fp8 MFMA GEMM on swizzled inputs --------------------------
// C = bf16(fast_tanh(outScale * (A @ B^T))), A:(M,1024) B:(N,1024) e4m3
// pre-swizzled (cvt2_fp8_sw). 128x128 tile, BK=64 bytes, 16 iters. m-fast grid.
__global__ __launch_bounds__(256) void gemm_fp8_bt(
    const unsigned char* __restrict__ A, const unsigned char* __restrict__ B,
    unsigned short* __restrict__ C, int M, int N, float outScale)
{
    __shared__ __align__(16) unsigned char As[8192];   // 8 subtiles x 1024B
    __shared__ __align__(16) unsigned char Bs[8192];
    const int tid = threadIdx.x;
    const int m0 = blockIdx.x * 128;
    const int n0 = blockIdx.y * 128;
    const int wid = tid >> 6;
    const int lane = tid & 63;
    const int quad = lane >> 4;
    const int l16 = lane & 15;
    const int wm = (wid >> 1) * 64;
    const int wn = (wid & 1) * 64;
    const int stA = wm >> 4;          // 0 or 4
    const int stB = wn >> 4;          // 0 or 4
    const int st = tid >> 6;          // staging subtile 0..3
    const int cl = (tid & 63) * 16;   // staging chunk byte

    f32x4 acc[4][4] = {};

    const unsigned char* Ab = A + ((size_t)(m0 >> 4) * 16) * 1024;  // KB=16
    const unsigned char* Bb = B + ((size_t)(n0 >> 4) * 16) * 1024;

    for (int kb = 0; kb < 16; kb++) {
        async16(&As[tid * 16],        Ab + ((size_t)st * 16 + kb) * 1024 + cl);
        async16(&As[4096 + tid * 16], Ab + ((size_t)(st + 4) * 16 + kb) * 1024 + cl);
        async16(&Bs[tid * 16],        Bb + ((size_t)st * 16 + kb) * 1024 + cl);
        async16(&Bs[4096 + tid * 16], Bb + ((size_t)(st + 4) * 16 + kb) * 1024 + cl);
        __syncthreads();

        lx2 a8[4], b8[4];
#pragma unroll
        for (int mt = 0; mt < 4; mt++)
            a8[mt] = *(const lx2*)&As[(stA + mt) * 1024 + lane * 16];
#pragma unroll
        for (int nt = 0; nt < 4; nt++)
            b8[nt] = *(const lx2*)&Bs[(stB + nt) * 1024 + lane * 16];
#pragma unroll
        for (int mt = 0; mt < 4; mt++)
#pragma unroll
            for (int nt = 0; nt < 4; nt++) {
                acc[mt][nt] = __builtin_amdgcn_mfma_f32_16x16x32_fp8_fp8(
                    a8[mt].x, b8[nt].x, acc[mt][nt], 0, 0, 0);
                acc[mt][nt] = __builtin_amdgcn_mfma_f32_16x16x32_fp8_fp8(
                    a8[mt].y, b8[nt].y, acc[mt][nt], 0, 0, 0);
            }
        __syncthreads();
    }

#pragma unroll
    for (int mt = 0; mt < 4; mt++)
#pragma unroll
        for (int nt = 0; nt < 4; nt++)
#pragma unroll
            for (int r = 0; r < 4; r++) {
                const int row = m0 + wm + mt * 16 + quad * 4 + r;
                const int col = n0 + wn + nt * 16 + l16;
                C[(size_t)row * N + col] = f2bf(fast_tanh(acc[mt][nt][r] * outScale));
            }
}

// ---------------- bf16 MFMA GEMM (qproj): C = A @ B^T, bf16 out -------------
__global__ __launch_bounds__(256) void gemm_bf16_bt(
    const unsigned short* __restrict__ A, const unsigned short* __restrict__ B,
    unsigned short* __restrict__ C, int M, int N, int K)
{
    __shared__ unsigned short As[128 * 32];   // 8 KB
    __shared__ unsigned short Bs[128 * 32];   // 8 KB
    const int tid = threadIdx.x;
    const int m0 = blockIdx.x * 128;
    const int n0 = blockIdx.y * 128;
    const int wid = tid >> 6;
    const int lane = tid & 63;
    const int quad = lane >> 4;
    const int l16 = lane & 15;
    const int wm = (wid >> 1) * 64;
    const int wn = (wid & 1) * 64;

    f32x4 acc[4][4] = {};

    const int r0 = tid >> 2;
    const int cc0 = (tid & 3) * 8;

    for (int k0 = 0; k0 < K; k0 += 32) {
        async16(&As[tid * 8],        A + (size_t)(m0 + r0) * K + k0 + cc0);
        async16(&As[2048 + tid * 8], A + (size_t)(m0 + 64 + r0) * K + k0 + cc0);
        async16(&Bs[tid * 8],        B + (size_t)(n0 + r0) * K + k0 + cc0);
        async16(&Bs[2048 + tid * 8], B + (size_t)(n0 + 64 + r0) * K + k0 + cc0);
        __syncthreads();

        bf16x8 af[4], bfr[4];
#pragma unroll
        for (int mt = 0; mt < 4; mt++)
            af[mt] = *(const bf16x8*)&As[(wm + mt * 16 + l16) * 32 + quad * 8];
#pragma unroll
        for (int nt = 0; nt < 4; nt++)
            bfr[nt] = *(const bf16x8*)&Bs[(wn + nt * 16 + l16) * 32 + quad * 8];
#pragma unroll
        for (int mt = 0; mt < 4; mt++)
#pragma unroll
            for (int nt = 0; nt < 4; nt++)
                acc[mt][nt] = __builtin_amdgcn_mfma_f32_16x16x32_bf16(
                    af[mt], bfr[nt], acc[mt][nt], 0, 0, 0);
        __syncthreads();
    }

#pragma unroll
    for (int mt = 0; mt < 4; mt++)
#pragma unroll
        for (int nt = 0; nt < 4; nt++)
#pragma unroll
            for (int r = 0; r < 4; r++) {
                const int row = m0 + wm + mt * 16 + quad * 4 + r;
                const int col = n0 + wn + nt * 16 + l16;
                C[(size_t)row * N + col] = f2bf(acc[mt][nt][r]);
            }
}

// ---------------- wql = ql @ WV^T (32 x 1024, K=1024), fp32, split-K -------
__global__ __launch_bounds__(256) void wql_kernel(
    const float* __restrict__ ql, const float* __restrict__ WV, float* __restrict__ wql)
{
    __shared__ float4 qls[32][32];      // [c][kq]   16 KB
    __shared__ float4 WVs[64][33];      // [n][kq]+pad 33.8 KB
    const int tid = threadIdx.x;
    const int n0 = blockIdx.x * 64;
    const int k0 = blockIdx.y * 128;

    for (int i = tid; i < 1024; i += 256)
        qls[i >> 5][i & 31] = *(const float4*)(ql + (size_t)(i >> 5) * D_MODEL + k0 + (i & 31) * 4);
    for (int i = tid; i < 2048; i += 256)
        WVs[i >> 5][i & 31] = *(const float4*)(WV + (size_t)(n0 + (i >> 5)) * D_MODEL + k0 + (i & 31) * 4);
    __syncthreads();

    const int n = tid & 63;
    const int c0 = (tid >> 6) * 8;
    float acc[8] = {};
    for (int kq = 0; kq < 32; kq++) {
        const float4 wv = WVs[n][kq];
#pragma unroll
        for (int c = 0; c < 8; c++) acc[c] += dot4(qls[c0 + c][kq], wv);
    }
#pragma unroll
    for (int c = 0; c < 8; c++)
        atomicAdd(&wql[(size_t)(c0 + c) * D_MODEL + n0 + n], acc[c]);
}

// ---------------- KV via MFMA ------------------------------------------------
// kv[((b*16+z)*32 + c)*512 + t] = sum_h tanh(H[b,t,z*64+h]) * wql[c,z*64+h]
__global__ __launch_bounds__(256) void kv_gemm(
    const float* __restrict__ H, const unsigned short* __restrict__ wql16,
    float* __restrict__ kv)
{
    __shared__ unsigned short Ks[128 * 64];  // 16 KB   [tl][h] bf16
    __shared__ float kvt[128 * 33];          // 16.9 KB [tl][c] padded
    const int chunk = blockIdx.x;
    const int z = blockIdx.y;
    const int b = chunk >> 2;
    const int t0 = (chunk & 3) * 128;
    const int tid = threadIdx.x;
    const int wid = tid >> 6;
    const int lane = tid & 63;
    const int quad = lane >> 4;
    const int l16 = lane & 15;

#pragma unroll
    for (int it = 0; it < 8; it++) {
        const int idx = it * 256 + tid;
        const int row = idx >> 4;
        const int c4 = (idx & 15) * 4;
        float4 v = *(const float4*)(H + ((size_t)b * T_LEN + t0 + row) * D_MODEL + z * D_K + c4);
        v = fast_tanh4(v);
        ushort4 o;
        o.x = f2bf(v.x); o.y = f2bf(v.y); o.z = f2bf(v.z); o.w = f2bf(v.w);
        *(ushort4*)&Ks[row * 64 + c4] = o;
    }
    bf16x8 bfr[2][2];
#pragma unroll
    for (int ct = 0; ct < 2; ct++)
#pragma unroll
        for (int kh = 0; kh < 2; kh++)
            bfr[ct][kh] = *(const bf16x8*)(wql16 +
                (size_t)(ct * 16 + l16) * D_MODEL + z * D_K + kh * 32 + quad * 8);
    __syncthreads();

    const int wt = wid * 32;
    f32x4 acc[2][2] = {};
#pragma unroll
    for (int tt = 0; tt < 2; tt++) {
        const bf16x8 a0 = *(const bf16x8*)&Ks[(wt + tt * 16 + l16) * 64 + quad * 8];
        const bf16x8 a1 = *(const bf16x8*)&Ks[(wt + tt * 16 + l16) * 64 + 32 + quad * 8];
#pragma unroll
        for (int ct = 0; ct < 2; ct++) {
            acc[tt][ct] = __builtin_amdgcn_mfma_f32_16x16x32_bf16(a0, bfr[ct][0], acc[tt][ct], 0, 0, 0);
            acc[tt][ct] = __builtin_amdgcn_mfma_f32_16x16x32_bf16(a1, bfr[ct][1], acc[tt][ct], 0, 0, 0);
        }
    }
#pragma unroll
    for (int tt = 0; tt < 2; tt++)
#pragma unroll
        for (int ct = 0; ct < 2; ct++)
#pragma unroll
            for (int r = 0; r < 4; r++)
                kvt[(wt + tt * 16 + quad * 4 + r) * 33 + ct * 16 + l16] = acc[tt][ct][r];
    __syncthreads();

    float* outb = kv + (((size_t)b * 16 + z) * 32) * 512 + t0;
#pragma unroll
    for (int it = 0; it < 4; it++) {
        const int idx = it * 256 + tid;
        const int c = idx >> 5;
        const int tq = (idx & 31) * 4;
        float4 v = make_float4(kvt[(tq + 0) * 33 + c], kvt[(tq + 1) * 33 + c],
                               kvt[(tq + 2) * 33 + c], kvt[(tq + 3) * 33 + c]);
        *(float4*)(outb + (size_t)c * 512 + tq) = v;
    }
}

// ---------------- Attention via MFMA: block per (b,z), 4 waves x 8 c-tiles ---
__global__ __launch_bounds__(256) void attn_mfma(
    const unsigned short* __restrict__ qproj, const unsigned short* __restrict__ wkt,
    const float* __restrict__ kv, float* __restrict__ out)
{
    __shared__ unsigned short wkts[512 * 64];   // 64 KB, [t][k]
    const int z = blockIdx.x;
    const int b = blockIdx.y;
    const int tid = threadIdx.x;
    const int wid = tid >> 6;
    const int lane = tid & 63;
    const int quad = lane >> 4;
    const int l16 = lane & 15;

    const unsigned short* wb = wkt + (size_t)(b * T_LEN) * D_MODEL + z * D_K;
#pragma unroll
    for (int it = 0; it < 16; it++) {
        const int chunk = it * 256 + tid;
        async16(&wkts[chunk * 8], wb + (size_t)(chunk >> 3) * D_MODEL + (chunk & 7) * 8);
    }

    bf16x8 af[8][2];
#pragma unroll
    for (int ct = 0; ct < 8; ct++)
#pragma unroll
        for (int kh = 0; kh < 2; kh++)
            af[ct][kh] = *(const bf16x8*)(qproj +
                (size_t)((wid * 8 + ct) * 16 + l16) * D_MODEL + z * D_K + kh * 32 + quad * 8);
    __syncthreads();

    float den[8][4], num[8][4];
#pragma unroll
    for (int ct = 0; ct < 8; ct++)
#pragma unroll
        for (int r = 0; r < 4; r++) { den[ct][r] = 0.f; num[ct][r] = 0.f; }

    const float* kvb = kv + (((size_t)b * 16 + z) * 32) * 512;
    for (int nt = 0; nt < 32; nt++) {
        const bf16x8 b0 = *(const bf16x8*)&wkts[(nt * 16 + l16) * 64 + quad * 8];
        const bf16x8 b1 = *(const bf16x8*)&wkts[(nt * 16 + l16) * 64 + 32 + quad * 8];
#pragma unroll
        for (int ct = 0; ct < 8; ct++) {
            f32x4 a = {};
            a = __builtin_amdgcn_mfma_f32_16x16x32_bf16(af[ct][0], b0, a, 0, 0, 0);
            a = __builtin_amdgcn_mfma_f32_16x16x32_bf16(af[ct][1], b1, a, 0, 0, 0);
            const float kvv = kvb[(size_t)(wid * 8 + ct) * 512 + nt * 16 + l16];
#pragma unroll
            for (int r = 0; r < 4; r++) {
                const float e = __expf(a[r]);
                den[ct][r] += e;
                num[ct][r] += e * kvv;
            }
        }
    }

#pragma unroll
    for (int ct = 0; ct < 8; ct++) {
        float s = 0.f;
#pragma unroll
        for (int r = 0; r < 4; r++) {
            float d = den[ct][r], n = num[ct][r];
#pragma unroll
            for (int off = 1; off < 16; off <<= 1) {
                d += __shfl_xor(d, off, 64);
                n += __shfl_xor(n, off, 64);
            }
            s += n / d;
        }
        s += __shfl_xor(s, 16, 64);
        s += __shfl_xor(s, 32, 64);
        if (lane == 0)
            atomicAdd(&out[b * N_CLASSES + wid * 8 + ct], s * (1.0f / 16.0f));
    }
}

extern "C" void kernel_launch(void* const* d_in, const int* in_sizes, int n_in,
                              void* d_out, int out_size, void* d_ws, size_t ws_size,
                              hipStream_t stream)
{
    const float* Q  = (const float*)d_in[0];   // (32,16,1024)
    const float* H  = (const float*)d_in[1];   // (32,512,1024)
    const float* ql = (const float*)d_in[2];   // (32,1024)
    const float* WQ = (const float*)d_in[3];   // (1024,1024)
    const float* WK = (const float*)d_in[4];
    const float* WV = (const float*)d_in[5];
    float* out = (float*)d_out;                // (32,32)

    char* ws = (char*)d_ws;
    // region A (0..33.5MB): Hf8 first (16.7MB); dead after wkt GEMM -> overlaid
    unsigned char*  Hf8   = (unsigned char*)(ws);                        // 16.7 MB
    unsigned short* wkt_b = (unsigned short*)(ws + (size_t)33554432);    // 33.5 MB
    float*          kv    = (float*)(ws + (size_t)67108864);             // 33.5 MB
    unsigned char*  WKf8  = (unsigned char*)(ws + (size_t)100663296);    // 1 MB
    // overlays into region A (written only after wkt GEMM):
    unsigned short* Qb      = (unsigned short*)(ws);                     // 1 MB
    unsigned short* WQb     = (unsigned short*)(ws + (size_t)(1 << 20)); // 2 MB
    unsigned short* qproj_b = (unsigned short*)(ws + (size_t)(3 << 20)); // 1 MB
    float*          wqlb    = (float*)(ws + (size_t)(4 << 20));          // 128 KB
    unsigned short* wqlb16  = (unsigned short*)(ws + (size_t)4718592);   // 64 KB

    hipMemsetAsync(d_out, 0, (size_t)out_size * sizeof(float), stream);

    dim3 thr(256);
    // fp8 swizzled conversions: H (scale 1), WK (x512: N(0,1e-3) subnormal in e4m3)
    cvt2_fp8_sw<<<dim3(17408), thr, 0, stream>>>(
        H, (int*)Hf8, 4194304,
        WK, (int*)WKf8, 262144, 512.0f);
    // wkt = fast_tanh((H8 @ WK8^T)/512)  (16384 x 1024), bf16 out. m-fast grid.
    gemm_fp8_bt<<<dim3(128, 8), thr, 0, stream>>>(Hf8, WKf8, wkt_b, 16384, 1024, 1.0f / 512.0f);
    // Hf8 dead -> overlay region A (Q + WQ bf16)
    cvt2_bf16<<<dim3(1536), thr, 0, stream>>>(
        (const float4*)Q, (ushort4*)Qb, 131072,
        (const float4*)WQ, (ushort4*)WQb, 262144);
    // qproj = Q @ WQ^T  (512 x 1024), bf16
    gemm_bf16_bt<<<dim3(4, 8), thr, 0, stream>>>(Qb, WQb, qproj_b, 512, 1024, 1024);
    // zero wqlb ONLY NOW (overlay ordering: cvt2_bf16 above writes 0..3MB)
    hipMemsetAsync(wqlb, 0, (size_t)N_CLASSES * D_MODEL * sizeof(float), stream);
    // Wql = ql @ WV^T  (32 x 1024), fp32 split-K
    wql_kernel<<<dim3(16, 8), thr, 0, stream>>>(ql, WV, wqlb);
    // wql -> bf16 for the kv MFMA
    cvt_bf16<<<dim3(32), thr, 0, stream>>>((const float4*)wqlb, (ushort4*)wqlb16, 8192);
    // kv(b,z,c,t) via MFMA
    kv_gemm<<<dim3(128, 16), thr, 0, stream>>>(H, wqlb16, kv);
    // fused scores -> softmax -> dot(kv) -> mean_s, atomic over z
    attn_mfma<<<dim3(16, 32), thr, 0, stream>>>(qproj_b, wkt_b, kv, out);
}